// Round 1
// baseline (101.213 us; speedup 1.0000x reference)
//
#include <hip/hip_runtime.h>

// MoE routing: softmax(logits[T,64]) -> top-2 (indices, values) per token.
// Output layout (floats): [0,2T) = indices as floats, [2T,4T) = prob values.

constexpr int E = 64;          // experts per token
constexpr int LANES_PER_TOKEN = 16;  // each lane holds 4 experts via float4

__global__ __launch_bounds__(256) void moe_route_kernel(
    const float* __restrict__ logits,
    float* __restrict__ out,
    int T, int nGroups)
{
    const int tid = blockIdx.x * blockDim.x + threadIdx.x;
    const int g0  = tid >> 4;          // global 16-lane group id
    const int sub = tid & 15;          // lane within group

    float* __restrict__ idx_out = out;
    float* __restrict__ val_out = out + 2ull * (unsigned long long)T;

    for (int row = g0; row < T; row += nGroups) {
        // Wave's 4 groups read 4 consecutive rows: 1 KiB contiguous per wave.
        const float4 x = *reinterpret_cast<const float4*>(
            logits + (size_t)row * E + sub * 4);

        // ---- row max (exact mirror of softmax's max subtraction) ----
        float m = fmaxf(fmaxf(x.x, x.y), fmaxf(x.z, x.w));
        #pragma unroll
        for (int mask = 1; mask < LANES_PER_TOKEN; mask <<= 1)
            m = fmaxf(m, __shfl_xor(m, mask));

        // ---- exp + sum ----
        float e0 = expf(x.x - m);
        float e1 = expf(x.y - m);
        float e2 = expf(x.z - m);
        float e3 = expf(x.w - m);
        float s = (e0 + e1) + (e2 + e3);
        #pragma unroll
        for (int mask = 1; mask < LANES_PER_TOKEN; mask <<= 1)
            s += __shfl_xor(s, mask);

        // ---- probs (divide like the reference; ties are on p, not e) ----
        float p[4];
        p[0] = e0 / s; p[1] = e1 / s; p[2] = e2 / s; p[3] = e3 / s;

        // ---- top-1 with lax.top_k tie-break (equal -> lower index) ----
        float bp = p[0]; int bi = sub * 4;
        #pragma unroll
        for (int j = 1; j < 4; ++j) {
            if (p[j] > bp) { bp = p[j]; bi = sub * 4 + j; }  // strict >: lower j kept on tie
        }
        #pragma unroll
        for (int mask = 1; mask < LANES_PER_TOKEN; mask <<= 1) {
            float op = __shfl_xor(bp, mask);
            int   oi = __shfl_xor(bi, mask);
            if (op > bp || (op == bp && oi < bi)) { bp = op; bi = oi; }
        }

        // ---- top-2: exclude global winner, repeat ----
        float bp2 = -1.0f; int bi2 = 0x7fffffff;
        #pragma unroll
        for (int j = 0; j < 4; ++j) {
            const int idx = sub * 4 + j;
            if (idx != bi && p[j] > bp2) { bp2 = p[j]; bi2 = idx; }
        }
        #pragma unroll
        for (int mask = 1; mask < LANES_PER_TOKEN; mask <<= 1) {
            float op = __shfl_xor(bp2, mask);
            int   oi = __shfl_xor(bi2, mask);
            if (op > bp2 || (op == bp2 && oi < bi2)) { bp2 = op; bi2 = oi; }
        }

        if (sub == 0) {
            float2 iv = make_float2((float)bi, (float)bi2);
            float2 pv = make_float2(bp, bp2);
            *reinterpret_cast<float2*>(idx_out + (size_t)row * 2) = iv;
            *reinterpret_cast<float2*>(val_out + (size_t)row * 2) = pv;
        }
    }
}

extern "C" void kernel_launch(void* const* d_in, const int* in_sizes, int n_in,
                              void* d_out, int out_size, void* d_ws, size_t ws_size,
                              hipStream_t stream) {
    const float* logits = (const float*)d_in[0];
    float* out = (float*)d_out;
    const int T = in_sizes[0] / E;   // 1048576

    const int threads = 256;
    const int groupsPerBlock = threads / LANES_PER_TOKEN;  // 16
    int blocks = 2048;                                      // G11 memory-bound cap
    const int maxBlocks = (T + groupsPerBlock - 1) / groupsPerBlock;
    if (blocks > maxBlocks) blocks = maxBlocks;
    const int nGroups = blocks * groupsPerBlock;

    moe_route_kernel<<<blocks, threads, 0, stream>>>(logits, out, T, nGroups);
}

// Round 2
// 88.377 us; speedup vs baseline: 1.1452x; 1.1452x over previous
//
#include <hip/hip_runtime.h>

// MoE routing: softmax(logits[T,64]) -> top-2 (indices, values) per token.
// Output layout (floats): [0,2T) = indices as floats, [2T,4T) = prob values.
//
// Strategy: select top-2 on raw logits (softmax is strictly monotone; matches
// np's p-based top_k except in ~1e-7 rounding-tie windows). Row max comes free
// as the top-1 value. Only the softmax denominator needs all 64 exps (__expf,
// 2 insts); only the 2 selected probs are ever divided (v_rcp, ~1 ulp,
// tolerance here is ~1e-3).

constexpr int E = 64;                // experts per token
constexpr int LANES_PER_TOKEN = 16;  // each lane holds 4 experts via float4

__global__ __launch_bounds__(256) void moe_route_kernel(
    const float* __restrict__ logits,
    float* __restrict__ out,
    int T, int nGroups)
{
    const int tid = blockIdx.x * blockDim.x + threadIdx.x;
    const int g0  = tid >> 4;          // global 16-lane group id
    const int sub = tid & 15;          // lane within group

    float* __restrict__ idx_out = out;
    float* __restrict__ val_out = out + 2ull * (unsigned long long)T;

    for (int row = g0; row < T; row += nGroups) {
        // Wave's 4 groups read 4 consecutive rows: 1 KiB contiguous per wave.
        const float4 x = *reinterpret_cast<const float4*>(
            logits + (size_t)row * E + sub * 4);

        // ---- in-lane top-2 on raw logits (strict >: lower index wins ties) ----
        float b1 = x.x; int i1 = sub * 4;
        float b2; int i2;
        if (x.y > b1) { b2 = b1; i2 = i1; b1 = x.y; i1 = sub * 4 + 1; }
        else          { b2 = x.y; i2 = sub * 4 + 1; }
        if (x.z > b1)      { b2 = b1; i2 = i1; b1 = x.z; i1 = sub * 4 + 2; }
        else if (x.z > b2) { b2 = x.z; i2 = sub * 4 + 2; }
        if (x.w > b1)      { b2 = b1; i2 = i1; b1 = x.w; i1 = sub * 4 + 3; }
        else if (x.w > b2) { b2 = x.w; i2 = sub * 4 + 3; }

        // ---- cross-lane top-2 merge (4 butterfly stages over 16 lanes) ----
        #pragma unroll
        for (int mask = 1; mask < LANES_PER_TOKEN; mask <<= 1) {
            float o1 = __shfl_xor(b1, mask);
            int   j1 = __shfl_xor(i1, mask);
            float o2 = __shfl_xor(b2, mask);
            int   j2 = __shfl_xor(i2, mask);
            // merge sorted pairs (b1,i1)>(b2,i2) and (o1,j1)>(o2,j2)
            if (o1 > b1 || (o1 == b1 && j1 < i1)) {
                // o1 becomes new best; new second = max(b1, o2) with tie->lower idx
                float nb2 = b1; int ni2 = i1;
                if (o2 > nb2 || (o2 == nb2 && j2 < ni2)) { nb2 = o2; ni2 = j2; }
                b2 = nb2; i2 = ni2; b1 = o1; i1 = j1;
            } else {
                // b1 stays best; second = max(b2, o1) with tie->lower idx
                if (o1 > b2 || (o1 == b2 && j1 < i2)) { b2 = o1; i2 = j1; }
            }
        }

        // ---- softmax denominator: s = sum(exp(x - m)), m == b1 ----
        const float m = b1;
        float s = __expf(x.x - m) + __expf(x.y - m)
                + __expf(x.z - m) + __expf(x.w - m);
        #pragma unroll
        for (int mask = 1; mask < LANES_PER_TOKEN; mask <<= 1)
            s += __shfl_xor(s, mask);

        if (sub == 0) {
            const float r = __builtin_amdgcn_rcpf(s);   // ~1 ulp
            const float p1 = r;                          // exp(m-m)/s = 1/s
            const float p2 = __expf(b2 - m) * r;
            *reinterpret_cast<float2*>(idx_out + (size_t)row * 2) =
                make_float2((float)i1, (float)i2);
            *reinterpret_cast<float2*>(val_out + (size_t)row * 2) =
                make_float2(p1, p2);
        }
    }
}

extern "C" void kernel_launch(void* const* d_in, const int* in_sizes, int n_in,
                              void* d_out, int out_size, void* d_ws, size_t ws_size,
                              hipStream_t stream) {
    const float* logits = (const float*)d_in[0];
    float* out = (float*)d_out;
    const int T = in_sizes[0] / E;   // 1048576

    const int threads = 256;
    const int groupsPerBlock = threads / LANES_PER_TOKEN;  // 16
    int blocks = 2048;                                      // G11 memory-bound cap
    const int maxBlocks = (T + groupsPerBlock - 1) / groupsPerBlock;
    if (blocks > maxBlocks) blocks = maxBlocks;
    const int nGroups = blocks * groupsPerBlock;

    moe_route_kernel<<<blocks, threads, 0, stream>>>(logits, out, T, nGroups);
}

// Round 3
// 49.433 us; speedup vs baseline: 2.0475x; 1.7878x over previous
//
#include <hip/hip_runtime.h>

// MoE routing: softmax(logits[T,64]) -> top-2 (indices, values) per token.
// Output layout (floats): [0,2T) = indices as floats, [2T,4T) = prob values.
//
// Layout: 4 lanes per token; lane `sub` owns elements {k*16 + sub*4 + c}
// (k,c in [0,4)), loaded as 4 interleaved float4s so load inst k reads
// 64 contiguous bytes per token-group (perfect coalescing).
// Top-2 via in-register sequential scan (exact lax.top_k tie semantics:
// increasing index order + strict '>'), then only 2 cross-lane merge stages.
// Softmax: top-1 IS the row max, p1 = 1/sum, only p2 needs another exp.

constexpr int E = 64;

__global__ __launch_bounds__(256) void moe_route_kernel(
    const float* __restrict__ logits,
    float* __restrict__ out,
    int T, int nGroups)
{
    const int tid = blockIdx.x * blockDim.x + threadIdx.x;
    const int g0  = tid >> 2;          // token-group id (4 lanes per token)
    const int sub = tid & 3;

    float* __restrict__ idx_out = out;
    float* __restrict__ val_out = out + 2ull * (unsigned long long)T;

    for (int row = g0; row < T; row += nGroups) {
        const float* rp = logits + (size_t)row * E + sub * 4;
        const float4 x0 = *reinterpret_cast<const float4*>(rp);
        const float4 x1 = *reinterpret_cast<const float4*>(rp + 16);
        const float4 x2 = *reinterpret_cast<const float4*>(rp + 32);
        const float4 x3 = *reinterpret_cast<const float4*>(rp + 48);

        // ---- in-lane sequential top-2 scan over 16 elems ----
        // local position p = k*4+c (inline consts); increasing global order.
        float b1 = x0.x; int p1l = 0;
        float b2 = -__builtin_inff(); int p2l = 0;
        #define SCAN(v, P) do {                                   \
            const float _v = (v); const bool c1 = _v > b1;        \
            const bool c2 = _v > b2;                              \
            const float ob1 = b1; const int op1 = p1l;            \
            b2  = c1 ? ob1 : (c2 ? _v  : b2);                     \
            p2l = c1 ? op1 : (c2 ? (P) : p2l);                    \
            b1  = c1 ? _v  : b1;                                  \
            p1l = c1 ? (P) : p1l;                                 \
        } while (0)
        SCAN(x0.y, 1);  SCAN(x0.z, 2);  SCAN(x0.w, 3);
        SCAN(x1.x, 4);  SCAN(x1.y, 5);  SCAN(x1.z, 6);  SCAN(x1.w, 7);
        SCAN(x2.x, 8);  SCAN(x2.y, 9);  SCAN(x2.z, 10); SCAN(x2.w, 11);
        SCAN(x3.x, 12); SCAN(x3.y, 13); SCAN(x3.z, 14); SCAN(x3.w, 15);
        #undef SCAN

        // decode local position -> global expert index: g = k*16 + sub*4 + c
        int i1 = ((p1l & 0xC) << 2) | (sub << 2) | (p1l & 3);
        int i2 = ((p2l & 0xC) << 2) | (sub << 2) | (p2l & 3);

        // ---- cross-lane top-2 merge: only 2 butterfly stages (4 lanes) ----
        #pragma unroll
        for (int mask = 1; mask <= 2; mask <<= 1) {
            const float o1 = __shfl_xor(b1, mask);
            const int   j1 = __shfl_xor(i1, mask);
            const float o2 = __shfl_xor(b2, mask);
            const int   j2 = __shfl_xor(i2, mask);
            if (o1 > b1 || (o1 == b1 && j1 < i1)) {
                float nb2 = b1; int ni2 = i1;
                if (o2 > nb2 || (o2 == nb2 && j2 < ni2)) { nb2 = o2; ni2 = j2; }
                b2 = nb2; i2 = ni2; b1 = o1; i1 = j1;
            } else {
                if (o1 > b2 || (o1 == b2 && j1 < i2)) { b2 = o1; i2 = j1; }
            }
        }

        // ---- softmax denominator: s = sum(exp(x - m)), m == b1 (global) ----
        const float m = b1;
        float s = __expf(x0.x - m) + __expf(x0.y - m)
                + __expf(x0.z - m) + __expf(x0.w - m)
                + __expf(x1.x - m) + __expf(x1.y - m)
                + __expf(x1.z - m) + __expf(x1.w - m)
                + __expf(x2.x - m) + __expf(x2.y - m)
                + __expf(x2.z - m) + __expf(x2.w - m)
                + __expf(x3.x - m) + __expf(x3.y - m)
                + __expf(x3.z - m) + __expf(x3.w - m);
        s += __shfl_xor(s, 1);
        s += __shfl_xor(s, 2);

        if (sub == 0) {
            const float r  = __builtin_amdgcn_rcpf(s);  // ~1 ulp
            const float pv1 = r;                         // exp(m-m)/s = 1/s
            const float pv2 = __expf(b2 - m) * r;
            *reinterpret_cast<float2*>(idx_out + (size_t)row * 2) =
                make_float2((float)i1, (float)i2);
            *reinterpret_cast<float2*>(val_out + (size_t)row * 2) =
                make_float2(pv1, pv2);
        }
    }
}

extern "C" void kernel_launch(void* const* d_in, const int* in_sizes, int n_in,
                              void* d_out, int out_size, void* d_ws, size_t ws_size,
                              hipStream_t stream) {
    const float* logits = (const float*)d_in[0];
    float* out = (float*)d_out;
    const int T = in_sizes[0] / E;   // 1048576

    const int threads = 256;
    const int groupsPerBlock = threads / 4;                 // 64 tokens/block
    int blocks = 2048;                                      // G11 memory-bound cap
    const int maxBlocks = (T + groupsPerBlock - 1) / groupsPerBlock;
    if (blocks > maxBlocks) blocks = maxBlocks;
    const int nGroups = blocks * groupsPerBlock;

    moe_route_kernel<<<blocks, threads, 0, stream>>>(logits, out, T, nGroups);
}